// Round 4
// baseline (502.409 us; speedup 1.0000x reference)
//
#include <hip/hip_runtime.h>
#include <hip/hip_bf16.h>

// GCN forward, bf16-MFMA + bf16 intermediates + XCD-striped pipelined GEMM.
//   H1 = F @ W1                  (bf16 MFMA, bf16 out, stride 1008)
//   X1 = relu(agg(H1)+b1)        (bf16 gather-agg, bf16 out padded to 1024)
//   H2 = X1 @ W2                 (bf16 MFMA, bf16 out, stride 504)
//   out = relu(relu(agg(H2)+b2) @ W3 + b3)   (fused agg+layer3)

#define N_NODES 20000
#define N_EDGES 200000
#define D_IN    1433
#define D_H1    1000
#define D_H2    500
#define D_OUT   7

#define MPAD    20096        // 157 * 128
#define K1PAD   1440
#define N1PAD   1024
#define K2PAD   1024
#define N2PAD   512
#define H1STR   1008
#define H2STR   504
#define MBLK    157          // m-blocks of 128

typedef __attribute__((ext_vector_type(8))) short short8;
typedef __attribute__((ext_vector_type(8))) unsigned short ushort8_t;
typedef __attribute__((ext_vector_type(4))) float f32x4;

// s_waitcnt imm: vmcnt[3:0]|[15:14], expcnt[6:4]=7 (ignore), lgkmcnt[11:8]=0xF (ignore)
#define WAIT_VM4 0xF74
#define WAIT_VM0 0xF70

__device__ __forceinline__ unsigned short bf16_rne(float x) {
    unsigned int u = __float_as_uint(x);
    u = (u + 0x7FFFu + ((u >> 16) & 1u)) >> 16;
    return (unsigned short)u;
}
__device__ __forceinline__ float bf16_up(unsigned short h) {
    return __uint_as_float((unsigned int)h << 16);
}

__device__ __forceinline__ void gl_lds16(const unsigned short* g, unsigned short* lds) {
    __builtin_amdgcn_global_load_lds(
        (const __attribute__((address_space(1))) unsigned int*)g,
        (__attribute__((address_space(3))) unsigned int*)lds, 16, 0, 0);
}

// ---------------------------------------------------------------- CSR build
__global__ __launch_bounds__(256) void count_deg(const int* __restrict__ dst,
                                                 int* __restrict__ offs) {
    int e = blockIdx.x * 256 + threadIdx.x;
    if (e < N_EDGES) atomicAdd(&offs[dst[e] + 1], 1);
}

__global__ __launch_bounds__(1024) void scan_inclusive(int* __restrict__ data, int n) {
    __shared__ int buf[1024];
    __shared__ int carry;
    int t = threadIdx.x;
    if (t == 0) carry = 0;
    __syncthreads();
    for (int base = 0; base < n; base += 1024) {
        int i = base + t;
        int v = (i < n) ? data[i] : 0;
        buf[t] = v;
        __syncthreads();
        #pragma unroll
        for (int s = 1; s < 1024; s <<= 1) {
            int u = (t >= s) ? buf[t - s] : 0;
            __syncthreads();
            buf[t] += u;
            __syncthreads();
        }
        int c = carry;
        if (i < n) data[i] = buf[t] + c;
        __syncthreads();
        if (t == 1023) carry = c + buf[1023];
        __syncthreads();
    }
}

__global__ __launch_bounds__(256) void fill_csr(const int* __restrict__ src,
                                                const int* __restrict__ dst,
                                                int* __restrict__ cursor,
                                                int* __restrict__ srcs) {
    int e = blockIdx.x * 256 + threadIdx.x;
    if (e < N_EDGES) {
        int pos = atomicAdd(&cursor[dst[e]], 1);
        srcs[pos] = src[e];
    }
}

// --------------------------------------------------------------- input casts
__global__ __launch_bounds__(256) void cast_features(const float* __restrict__ F,
                                                     unsigned int* __restrict__ out) {
    int row = blockIdx.x;
    int t = threadIdx.x;
    const float* fr = F + (size_t)row * D_IN;
    bool live = row < N_NODES;
    for (int kk = t; kk < K1PAD / 2; kk += 256) {
        int k0 = kk * 2;
        float a = (live && k0     < D_IN) ? fr[k0]     : 0.f;
        float b = (live && k0 + 1 < D_IN) ? fr[k0 + 1] : 0.f;
        out[(size_t)row * (K1PAD / 2) + kk] =
            (unsigned int)bf16_rne(a) | ((unsigned int)bf16_rne(b) << 16);
    }
}

template <int SR, int SC, int DR, int DC>
__global__ __launch_bounds__(256) void transpose_cast_pad(const float* __restrict__ src,
                                                          unsigned short* __restrict__ dst) {
    __shared__ float tile[32][33];
    int c0 = blockIdx.x * 32;
    int r0 = blockIdx.y * 32;
    int tx = threadIdx.x & 31, ty = threadIdx.x >> 5;
    #pragma unroll
    for (int p = 0; p < 4; ++p) {
        int r = r0 + ty + p * 8, c = c0 + tx;
        tile[ty + p * 8][tx] = (r < SR && c < SC) ? src[(size_t)r * SC + c] : 0.f;
    }
    __syncthreads();
    #pragma unroll
    for (int p = 0; p < 4; ++p) {
        int dr = c0 + ty + p * 8;
        int dc = r0 + tx;
        if (dr < DR && dc < DC) dst[(size_t)dr * DC + dc] = bf16_rne(tile[tx][ty + p * 8]);
    }
}

// -------------------------------------------------------------- bf16 MFMA GEMM
// C[M,N](bf16, stride OSTR) = A[MPAD,KPAD] @ B^T rows[NPAD,KPAD].
// Flat grid 8*NB*ceil(MBLK/8): xcd=bid&7 owns m-blocks {xcd, xcd+8, ...} ->
// A fetched once chip-wide; NB blocks sharing an A-tile are bid-adjacent on
// one XCD. 2-stage LDS double-buffer, raw vmcnt(4) waits (prefetch overlaps
// one full iteration of MFMA + barriers).
template <int KPAD, int NB>
__global__ __launch_bounds__(256) void gemm_mfma(const unsigned short* __restrict__ A,
                                                 const unsigned short* __restrict__ B,
                                                 unsigned short* __restrict__ C,
                                                 int M, int N, int OSTR) {
    __shared__ __align__(16) unsigned short sA[2][128 * 32];
    __shared__ __align__(16) unsigned short sB[2][128 * 32];
    const int bid = blockIdx.x;
    const int xcd = bid & 7;
    const int tt  = bid >> 3;
    const int nb  = tt % NB;
    const int mb  = (tt / NB) * 8 + xcd;
    if (mb >= MBLK) return;

    const int t = threadIdx.x;
    const int w = t >> 6, lane = t & 63;
    const int m0 = mb * 128, n0 = nb * 128;
    const int wm = (w >> 1) * 64, wn = (w & 1) * 64;
    const int srow = lane >> 2;          // staging row within 16-row group
    const int skc  = (lane & 3) * 8;     // staging k-chunk offset
    const int mrow = lane & 15, quad = lane >> 4;

    const unsigned short* Abase = A + (size_t)m0 * KPAD + skc;
    const unsigned short* Bbase = B + (size_t)n0 * KPAD + skc;

    f32x4 acc[4][4] = {};
    const int niter = KPAD / 32;

    auto stage = [&](int k, int buf) {  // 4 gl_lds16 per lane (2 A + 2 B)
        const int k0 = k * 32;
        #pragma unroll
        for (int c = 0; c < 2; ++c) {
            int rbase = c * 64 + w * 16;
            gl_lds16(Abase + (size_t)(rbase + srow) * KPAD + k0, &sA[buf][rbase * 32]);
            gl_lds16(Bbase + (size_t)(rbase + srow) * KPAD + k0, &sB[buf][rbase * 32]);
        }
    };
    auto compute = [&](int cur) {
        short8 af[4], bf[4];
        #pragma unroll
        for (int mt = 0; mt < 4; ++mt)
            af[mt] = *(const short8*)&sA[cur][(wm + mt * 16 + mrow) * 32 + quad * 8];
        #pragma unroll
        for (int nt = 0; nt < 4; ++nt)
            bf[nt] = *(const short8*)&sB[cur][(wn + nt * 16 + mrow) * 32 + quad * 8];
        #pragma unroll
        for (int mt = 0; mt < 4; ++mt)
            #pragma unroll
            for (int nt = 0; nt < 4; ++nt)
                acc[mt][nt] = __builtin_amdgcn_mfma_f32_16x16x32_bf16(
                    af[mt], bf[nt], acc[mt][nt], 0, 0, 0);
    };

    stage(0, 0);
    for (int k = 0; k < niter - 1; ++k) {
        const int cur = k & 1;
        stage(k + 1, cur ^ 1);
        __builtin_amdgcn_s_waitcnt(WAIT_VM4);   // wait buf[cur] (issued last iter)
        __asm__ volatile("" ::: "memory");
        __builtin_amdgcn_s_barrier();
        __asm__ volatile("" ::: "memory");
        compute(cur);
        __asm__ volatile("" ::: "memory");
        __builtin_amdgcn_s_barrier();           // buf[cur] free for overwrite
        __asm__ volatile("" ::: "memory");
    }
    __builtin_amdgcn_s_waitcnt(WAIT_VM0);
    __asm__ volatile("" ::: "memory");
    __builtin_amdgcn_s_barrier();
    __asm__ volatile("" ::: "memory");
    compute((niter - 1) & 1);

    // C/D layout: col = lane&15, row = quad*4 + reg
    #pragma unroll
    for (int mt = 0; mt < 4; ++mt) {
        int m = m0 + wm + mt * 16 + quad * 4;
        #pragma unroll
        for (int nt = 0; nt < 4; ++nt) {
            int n = n0 + wn + nt * 16 + mrow;
            if (n >= N) continue;
            #pragma unroll
            for (int r = 0; r < 4; ++r)
                if (m + r < M) C[(size_t)(m + r) * OSTR + n] = bf16_rne(acc[mt][nt][r]);
        }
    }
}

// -------------------------------- agg1: X1 = relu(agg(H1)+b1), bf16 -> bf16
__global__ __launch_bounds__(128) void agg1_bf16(const unsigned short* __restrict__ H,
                                                 const int* __restrict__ offs,
                                                 const int* __restrict__ srcs,
                                                 const float* __restrict__ bias,
                                                 unsigned short* __restrict__ X) {
    __shared__ int sl[128];
    const int i = blockIdx.x, t = threadIdx.x;
    const int beg = offs[i], end = offs[i + 1];
    const bool active = t < 125;
    float s[8] = {};
    for (int base = beg; base < end; base += 128) {
        int n = min(128, end - base);
        __syncthreads();
        if (t < n) sl[t] = srcs[base + t];
        __syncthreads();
        if (active) {
            for (int e = 0; e < n; ++e) {
                ushort8_t v = *(const ushort8_t*)(H + (size_t)sl[e] * H1STR + t * 8);
                #pragma unroll
                for (int u = 0; u < 8; ++u) s[u] += bf16_up(v[u]);
            }
        }
    }
    ushort8_t o = (ushort8_t)0;
    if (active) {
        #pragma unroll
        for (int u = 0; u < 8; ++u)
            o[u] = bf16_rne(fmaxf(s[u] + bias[t * 8 + u], 0.f));
    }
    *(ushort8_t*)(X + (size_t)i * K2PAD + t * 8) = o;
}

// ---------------- agg2 + layer3: out = relu(relu(agg(H2)+b2) @ W3 + b3)
__global__ __launch_bounds__(128) void agg2_out(const unsigned short* __restrict__ H,
                                                const int* __restrict__ offs,
                                                const int* __restrict__ srcs,
                                                const float* __restrict__ b2,
                                                const float* __restrict__ W3,
                                                const float* __restrict__ b3,
                                                float* __restrict__ out) {
    __shared__ int sl[128];
    __shared__ float red[2][8];
    const int i = blockIdx.x, t = threadIdx.x;
    const int beg = offs[i], end = offs[i + 1];
    const bool active = t < 125;
    float s[4] = {};
    for (int base = beg; base < end; base += 128) {
        int n = min(128, end - base);
        __syncthreads();
        if (t < n) sl[t] = srcs[base + t];
        __syncthreads();
        if (active) {
            for (int e = 0; e < n; ++e) {
                ushort4 v = *(const ushort4*)(H + (size_t)sl[e] * H2STR + t * 4);
                s[0] += bf16_up(v.x); s[1] += bf16_up(v.y);
                s[2] += bf16_up(v.z); s[3] += bf16_up(v.w);
            }
        }
    }
    float acc[D_OUT] = {};
    if (active) {
        #pragma unroll
        for (int u = 0; u < 4; ++u) {
            float x = fmaxf(s[u] + b2[t * 4 + u], 0.f);
            const float* w = W3 + (size_t)(t * 4 + u) * D_OUT;
            #pragma unroll
            for (int j = 0; j < D_OUT; ++j) acc[j] += x * w[j];
        }
    }
    #pragma unroll
    for (int j = 0; j < D_OUT; ++j)
        #pragma unroll
        for (int off = 32; off; off >>= 1) acc[j] += __shfl_down(acc[j], off);
    const int lane = t & 63, wave = t >> 6;
    if (lane == 0) {
        #pragma unroll
        for (int j = 0; j < D_OUT; ++j) red[wave][j] = acc[j];
    }
    __syncthreads();
    if (t == 0) {
        #pragma unroll
        for (int j = 0; j < D_OUT; ++j)
            out[(size_t)i * D_OUT + j] = fmaxf(red[0][j] + red[1][j] + b3[j], 0.f);
    }
}

// ---------------------------------------------------------------------- launch
extern "C" void kernel_launch(void* const* d_in, const int* in_sizes, int n_in,
                              void* d_out, int out_size, void* d_ws, size_t ws_size,
                              hipStream_t stream) {
    const float* features = (const float*)d_in[0];
    const int*   src      = (const int*)d_in[1];
    const int*   dst      = (const int*)d_in[2];
    const float* W1       = (const float*)d_in[3];
    const float* b1       = (const float*)d_in[4];
    const float* W2       = (const float*)d_in[5];
    const float* b2       = (const float*)d_in[6];
    const float* W3       = (const float*)d_in[7];
    const float* b3       = (const float*)d_in[8];
    float* out = (float*)d_out;

    char* ws = (char*)d_ws;
    unsigned short* Fbf  = (unsigned short*)(ws + 0);          // [MPAD][K1PAD]  57,876,480 B
    unsigned short* X1bf = (unsigned short*)(ws + 0);          // [MPAD][K2PAD]  41,156,608 B
    unsigned short* H1   = (unsigned short*)(ws + 57876480);   // [20000][H1STR] 40,320,000 B
    unsigned short* H2   = (unsigned short*)(ws + 57876480);   // [20000][H2STR] 20,160,000 B
    unsigned short* W1T  = (unsigned short*)(ws + 98196480);   // [N1PAD][K1PAD]  2,949,120 B
    unsigned short* W2T  = (unsigned short*)(ws + 101145600);  // [N2PAD][K2PAD]  1,048,576 B
    int* offs   = (int*)(ws + 102194176);
    int* cursor = (int*)(ws + 102274304);
    int* srcs   = (int*)(ws + 102354432);

    // ---- CSR build
    hipMemsetAsync(offs, 0, (N_NODES + 1) * sizeof(int), stream);
    count_deg<<<(N_EDGES + 255) / 256, 256, 0, stream>>>(dst, offs);
    scan_inclusive<<<1, 1024, 0, stream>>>(offs, N_NODES + 1);
    hipMemcpyAsync(cursor, offs, N_NODES * sizeof(int), hipMemcpyDeviceToDevice, stream);
    fill_csr<<<(N_EDGES + 255) / 256, 256, 0, stream>>>(src, dst, cursor, srcs);

    // ---- casts
    cast_features<<<MPAD, 256, 0, stream>>>(features, (unsigned int*)Fbf);
    transpose_cast_pad<D_IN, D_H1, N1PAD, K1PAD>
        <<<dim3(N1PAD / 32, K1PAD / 32), 256, 0, stream>>>(W1, W1T);
    transpose_cast_pad<D_H1, D_H2, N2PAD, K2PAD>
        <<<dim3(N2PAD / 32, K2PAD / 32), 256, 0, stream>>>(W2, W2T);

    // ---- layer 1: H1 = F @ W1; X1 = relu(agg(H1)+b1)
    gemm_mfma<K1PAD, N1PAD / 128><<<8 * (N1PAD / 128) * 20, 256, 0, stream>>>(
        Fbf, W1T, H1, N_NODES, D_H1, H1STR);
    hipMemsetAsync(ws + (size_t)N_NODES * K2PAD * 2, 0,
                   (size_t)(MPAD - N_NODES) * K2PAD * 2, stream);
    agg1_bf16<<<N_NODES, 128, 0, stream>>>(H1, offs, srcs, b1, X1bf);

    // ---- layer 2: H2 = X1 @ W2; out = fused agg2 + layer3
    gemm_mfma<K2PAD, N2PAD / 128><<<8 * (N2PAD / 128) * 20, 256, 0, stream>>>(
        X1bf, W2T, H2, N_NODES, D_H2, H2STR);
    agg2_out<<<N_NODES, 128, 0, stream>>>(H2, offs, srcs, b2, W3, b3, out);
}

// Round 5
// 457.454 us; speedup vs baseline: 1.0983x; 1.0983x over previous
//
#include <hip/hip_runtime.h>
#include <hip/hip_bf16.h>

// GCN forward, bf16-MFMA + bf16 intermediates + XCD m-striping + LDS XOR-swizzle.
//   H1 = F @ W1                  (bf16 MFMA, bf16 out, stride 1008)
//   X1 = relu(agg(H1)+b1)        (bf16 gather-agg, bf16 out padded to 1024)
//   H2 = X1 @ W2                 (bf16 MFMA, bf16 out, stride 504)
//   out = relu(relu(agg(H2)+b2) @ W3 + b3)   (fused agg+layer3)

#define N_NODES 20000
#define N_EDGES 200000
#define D_IN    1433
#define D_H1    1000
#define D_H2    500
#define D_OUT   7

#define MPAD    20096        // 157 * 128
#define K1PAD   1440
#define N1PAD   1024
#define K2PAD   1024
#define N2PAD   512
#define H1STR   1008
#define H2STR   504
#define MBLK    157          // m-blocks of 128

typedef __attribute__((ext_vector_type(8))) short short8;
typedef __attribute__((ext_vector_type(8))) unsigned short ushort8_t;
typedef __attribute__((ext_vector_type(4))) float f32x4;

__device__ __forceinline__ unsigned short bf16_rne(float x) {
    unsigned int u = __float_as_uint(x);
    u = (u + 0x7FFFu + ((u >> 16) & 1u)) >> 16;
    return (unsigned short)u;
}
__device__ __forceinline__ float bf16_up(unsigned short h) {
    return __uint_as_float((unsigned int)h << 16);
}

__device__ __forceinline__ void gl_lds16(const unsigned short* g, unsigned short* lds) {
    __builtin_amdgcn_global_load_lds(
        (const __attribute__((address_space(1))) unsigned int*)g,
        (__attribute__((address_space(3))) unsigned int*)lds, 16, 0, 0);
}

// ---------------------------------------------------------------- CSR build
__global__ __launch_bounds__(256) void count_deg(const int* __restrict__ dst,
                                                 int* __restrict__ offs) {
    int e = blockIdx.x * 256 + threadIdx.x;
    if (e < N_EDGES) atomicAdd(&offs[dst[e] + 1], 1);
}

// single-block inclusive scan via wave shuffles; also fills cursor[i] = offs[i]
__global__ __launch_bounds__(1024) void scan_csr(int* __restrict__ offs,
                                                 int* __restrict__ cursor, int n) {
    __shared__ int wsum[16];
    __shared__ int s_carry;
    const int t = threadIdx.x, lane = t & 63, wv = t >> 6;
    if (t == 0) s_carry = 0;
    __syncthreads();
    for (int base = 0; base < n; base += 1024) {
        int i = base + t;
        int v = (i < n) ? offs[i] : 0;
        #pragma unroll
        for (int s = 1; s < 64; s <<= 1) {
            int u = __shfl_up(v, s, 64);
            if (lane >= s) v += u;
        }
        if (lane == 63) wsum[wv] = v;
        __syncthreads();
        int prefix = s_carry;
        for (int k = 0; k < wv; ++k) prefix += wsum[k];
        v += prefix;
        if (i < n) {
            offs[i] = v;
            if (i < N_NODES) cursor[i] = v;
        }
        __syncthreads();
        if (t == 1023) s_carry = v;
        // next-iteration barrier orders this write before the next reads
    }
}

__global__ __launch_bounds__(256) void fill_csr(const int* __restrict__ src,
                                                const int* __restrict__ dst,
                                                int* __restrict__ cursor,
                                                int* __restrict__ srcs) {
    int e = blockIdx.x * 256 + threadIdx.x;
    if (e < N_EDGES) {
        int pos = atomicAdd(&cursor[dst[e]], 1);
        srcs[pos] = src[e];
    }
}

// --------------------------------------------------------------- input casts
__global__ __launch_bounds__(256) void cast_features(const float* __restrict__ F,
                                                     unsigned int* __restrict__ out) {
    int row = blockIdx.x;
    int t = threadIdx.x;
    const float* fr = F + (size_t)row * D_IN;
    bool live = row < N_NODES;
    for (int kk = t; kk < K1PAD / 2; kk += 256) {
        int k0 = kk * 2;
        float a = (live && k0     < D_IN) ? fr[k0]     : 0.f;
        float b = (live && k0 + 1 < D_IN) ? fr[k0 + 1] : 0.f;
        out[(size_t)row * (K1PAD / 2) + kk] =
            (unsigned int)bf16_rne(a) | ((unsigned int)bf16_rne(b) << 16);
    }
}

template <int SR, int SC, int DR, int DC>
__global__ __launch_bounds__(256) void transpose_cast_pad(const float* __restrict__ src,
                                                          unsigned short* __restrict__ dst) {
    __shared__ float tile[32][33];
    int c0 = blockIdx.x * 32;
    int r0 = blockIdx.y * 32;
    int tx = threadIdx.x & 31, ty = threadIdx.x >> 5;
    #pragma unroll
    for (int p = 0; p < 4; ++p) {
        int r = r0 + ty + p * 8, c = c0 + tx;
        tile[ty + p * 8][tx] = (r < SR && c < SC) ? src[(size_t)r * SC + c] : 0.f;
    }
    __syncthreads();
    #pragma unroll
    for (int p = 0; p < 4; ++p) {
        int dr = c0 + ty + p * 8;
        int dc = r0 + tx;
        if (dr < DR && dc < DC) dst[(size_t)dr * DC + dc] = bf16_rne(tile[tx][ty + p * 8]);
    }
}

// -------------------------------------------------------------- bf16 MFMA GEMM
// C[M,N](bf16, stride OSTR) = A[MPAD,KPAD] @ B^T rows[NPAD,KPAD].
// XCD m-striping: xcd = bid&7 owns m-blocks {xcd, xcd+8, ...} -> A fetched once
// chip-wide (verified: FETCH 234->63.7 MB). Single LDS buffer, compiler-
// scheduled waits (beat explicit vmcnt pipeline by 8%).
// LDS XOR-swizzle: slot s of row r holds k-chunk s ^ ((r>>1)&3) -> fragment
// ds_read_b128 phases hit distinct (parity,slot) bank groups: conflict-free.
template <int KPAD, int NB>
__global__ __launch_bounds__(256) void gemm_mfma(const unsigned short* __restrict__ A,
                                                 const unsigned short* __restrict__ B,
                                                 unsigned short* __restrict__ C,
                                                 int M, int N, int OSTR) {
    __shared__ __align__(16) unsigned short sA[128 * 32];
    __shared__ __align__(16) unsigned short sB[128 * 32];
    const int bid = blockIdx.x;
    const int xcd = bid & 7;
    const int tt  = bid >> 3;
    const int nb  = tt % NB;
    const int mb  = (tt / NB) * 8 + xcd;
    if (mb >= MBLK) return;

    const int t = threadIdx.x;
    const int w = t >> 6, lane = t & 63;
    const int m0 = mb * 128, n0 = nb * 128;
    const int wm = (w >> 1) * 64, wn = (w & 1) * 64;

    const int srow = lane >> 2;                                  // staging row in 16-group
    const int skc  = ((lane & 3) ^ ((lane >> 3) & 3)) * 8;       // XOR-swizzled k-chunk
    const int mrow = lane & 15, quad = lane >> 4;
    const int rslot = ((quad ^ ((mrow >> 1) & 3)) & 3) * 8;      // read-slot offset (shorts)

    const unsigned short* Aptr = A + (size_t)(m0 + srow) * KPAD + skc;
    const unsigned short* Bptr = B + (size_t)(n0 + srow) * KPAD + skc;

    f32x4 acc[4][4] = {};

    for (int k0 = 0; k0 < KPAD; k0 += 32) {
        #pragma unroll
        for (int c = 0; c < 2; ++c) {
            int rbase = c * 64 + w * 16;
            gl_lds16(Aptr + (size_t)rbase * KPAD, &sA[rbase * 32]);
            gl_lds16(Bptr + (size_t)rbase * KPAD, &sB[rbase * 32]);
        }
        Aptr += 32; Bptr += 32;
        __syncthreads();

        short8 af[4], bf[4];
        #pragma unroll
        for (int mt = 0; mt < 4; ++mt)
            af[mt] = *(const short8*)&sA[(wm + mt * 16 + mrow) * 32 + rslot];
        #pragma unroll
        for (int nt = 0; nt < 4; ++nt)
            bf[nt] = *(const short8*)&sB[(wn + nt * 16 + mrow) * 32 + rslot];
        #pragma unroll
        for (int mt = 0; mt < 4; ++mt)
            #pragma unroll
            for (int nt = 0; nt < 4; ++nt)
                acc[mt][nt] = __builtin_amdgcn_mfma_f32_16x16x32_bf16(
                    af[mt], bf[nt], acc[mt][nt], 0, 0, 0);
        __syncthreads();
    }

    // C/D layout: col = lane&15, row = quad*4 + reg
    #pragma unroll
    for (int mt = 0; mt < 4; ++mt) {
        int m = m0 + wm + mt * 16 + quad * 4;
        #pragma unroll
        for (int nt = 0; nt < 4; ++nt) {
            int n = n0 + wn + nt * 16 + mrow;
            if (n >= N) continue;
            #pragma unroll
            for (int r = 0; r < 4; ++r)
                if (m + r < M) C[(size_t)(m + r) * OSTR + n] = bf16_rne(acc[mt][nt][r]);
        }
    }
}

// -------------------------------- agg1: X1 = relu(agg(H1)+b1), bf16 -> bf16
// grid = MPAD: blocks >= N_NODES emit zero pad rows. No LDS/barriers: srcs[e]
// is a uniform (scalar) load; row gathers independent across e -> MLP-pipelined.
__global__ __launch_bounds__(128) void agg1_bf16(const unsigned short* __restrict__ H,
                                                 const int* __restrict__ offs,
                                                 const int* __restrict__ srcs,
                                                 const float* __restrict__ bias,
                                                 unsigned short* __restrict__ X) {
    const int i = blockIdx.x, t = threadIdx.x;
    const bool active = t < 125;
    const int tc = active ? t : 124;          // lanes 125-127 duplicate lane 124's loads
    ushort8_t o = (ushort8_t)0;
    if (i < N_NODES) {
        const int beg = offs[i], end = offs[i + 1];
        float s[8] = {};
        for (int e = beg; e < end; ++e) {
            const int j = srcs[e];
            ushort8_t v = *(const ushort8_t*)(H + (size_t)j * H1STR + tc * 8);
            #pragma unroll
            for (int u = 0; u < 8; ++u) s[u] += bf16_up(v[u]);
        }
        if (active) {
            #pragma unroll
            for (int u = 0; u < 8; ++u)
                o[u] = bf16_rne(fmaxf(s[u] + bias[t * 8 + u], 0.f));
        }
    }
    *(ushort8_t*)(X + (size_t)i * K2PAD + t * 8) = o;
}

// ---------------- agg2 + layer3: out = relu(relu(agg(H2)+b2) @ W3 + b3)
__global__ __launch_bounds__(128) void agg2_out(const unsigned short* __restrict__ H,
                                                const int* __restrict__ offs,
                                                const int* __restrict__ srcs,
                                                const float* __restrict__ b2,
                                                const float* __restrict__ W3,
                                                const float* __restrict__ b3,
                                                float* __restrict__ out) {
    __shared__ float red[2][8];
    const int i = blockIdx.x, t = threadIdx.x;
    const bool active = t < 125;
    const int tc = active ? t : 124;
    const int beg = offs[i], end = offs[i + 1];
    float s[4] = {};
    for (int e = beg; e < end; ++e) {
        const int j = srcs[e];
        ushort4 v = *(const ushort4*)(H + (size_t)j * H2STR + tc * 4);
        s[0] += bf16_up(v.x); s[1] += bf16_up(v.y);
        s[2] += bf16_up(v.z); s[3] += bf16_up(v.w);
    }
    float acc[D_OUT] = {};
    if (active) {
        #pragma unroll
        for (int u = 0; u < 4; ++u) {
            float x = fmaxf(s[u] + b2[t * 4 + u], 0.f);
            const float* wr = W3 + (size_t)(t * 4 + u) * D_OUT;
            #pragma unroll
            for (int j = 0; j < D_OUT; ++j) acc[j] += x * wr[j];
        }
    }
    #pragma unroll
    for (int j = 0; j < D_OUT; ++j)
        #pragma unroll
        for (int off = 32; off; off >>= 1) acc[j] += __shfl_down(acc[j], off);
    const int lane = t & 63, wave = t >> 6;
    if (lane == 0) {
        #pragma unroll
        for (int j = 0; j < D_OUT; ++j) red[wave][j] = acc[j];
    }
    __syncthreads();
    if (t == 0) {
        #pragma unroll
        for (int j = 0; j < D_OUT; ++j)
            out[(size_t)i * D_OUT + j] = fmaxf(red[0][j] + red[1][j] + b3[j], 0.f);
    }
}

// ---------------------------------------------------------------------- launch
extern "C" void kernel_launch(void* const* d_in, const int* in_sizes, int n_in,
                              void* d_out, int out_size, void* d_ws, size_t ws_size,
                              hipStream_t stream) {
    const float* features = (const float*)d_in[0];
    const int*   src      = (const int*)d_in[1];
    const int*   dst      = (const int*)d_in[2];
    const float* W1       = (const float*)d_in[3];
    const float* b1       = (const float*)d_in[4];
    const float* W2       = (const float*)d_in[5];
    const float* b2       = (const float*)d_in[6];
    const float* W3       = (const float*)d_in[7];
    const float* b3       = (const float*)d_in[8];
    float* out = (float*)d_out;

    char* ws = (char*)d_ws;
    unsigned short* Fbf  = (unsigned short*)(ws + 0);          // [MPAD][K1PAD]  57,876,480 B
    unsigned short* X1bf = (unsigned short*)(ws + 0);          // [MPAD][K2PAD]  41,156,608 B
    unsigned short* H1   = (unsigned short*)(ws + 57876480);   // [20000][H1STR] 40,320,000 B
    unsigned short* H2   = (unsigned short*)(ws + 57876480);   // [20000][H2STR] 20,160,000 B
    unsigned short* W1T  = (unsigned short*)(ws + 98196480);   // [N1PAD][K1PAD]  2,949,120 B
    unsigned short* W2T  = (unsigned short*)(ws + 101145600);  // [N2PAD][K2PAD]  1,048,576 B
    int* offs   = (int*)(ws + 102194176);
    int* cursor = (int*)(ws + 102274304);
    int* srcs   = (int*)(ws + 102354432);

    // ---- CSR build
    hipMemsetAsync(offs, 0, (N_NODES + 1) * sizeof(int), stream);
    count_deg<<<(N_EDGES + 255) / 256, 256, 0, stream>>>(dst, offs);
    scan_csr<<<1, 1024, 0, stream>>>(offs, cursor, N_NODES + 1);
    fill_csr<<<(N_EDGES + 255) / 256, 256, 0, stream>>>(src, dst, cursor, srcs);

    // ---- casts
    cast_features<<<MPAD, 256, 0, stream>>>(features, (unsigned int*)Fbf);
    transpose_cast_pad<D_IN, D_H1, N1PAD, K1PAD>
        <<<dim3(N1PAD / 32, K1PAD / 32), 256, 0, stream>>>(W1, W1T);
    transpose_cast_pad<D_H1, D_H2, N2PAD, K2PAD>
        <<<dim3(N2PAD / 32, K2PAD / 32), 256, 0, stream>>>(W2, W2T);

    // ---- layer 1: H1 = F @ W1; X1 = relu(agg(H1)+b1) (pad rows zeroed in-kernel)
    gemm_mfma<K1PAD, N1PAD / 128><<<8 * (N1PAD / 128) * 20, 256, 0, stream>>>(
        Fbf, W1T, H1, N_NODES, D_H1, H1STR);
    agg1_bf16<<<MPAD, 128, 0, stream>>>(H1, offs, srcs, b1, X1bf);

    // ---- layer 2: H2 = X1 @ W2; out = fused agg2 + layer3
    gemm_mfma<K2PAD, N2PAD / 128><<<8 * (N2PAD / 128) * 20, 256, 0, stream>>>(
        X1bf, W2T, H2, N_NODES, D_H2, H2STR);
    agg2_out<<<N_NODES, 128, 0, stream>>>(H2, offs, srcs, b2, W3, b3, out);
}

// Round 6
// 439.332 us; speedup vs baseline: 1.1436x; 1.0412x over previous
//
#include <hip/hip_runtime.h>
#include <hip/hip_bf16.h>

// GCN forward, bf16-MFMA + bf16 intermediates + XCD m-striping + BK=64 XOR-swizzle.
//   H1 = F @ W1                  (bf16 MFMA, bf16 out, stride 1008)
//   X1 = relu(agg(H1)+b1)        (bf16 gather-agg, bf16 out padded to 1024)
//   H2 = X1 @ W2                 (bf16 MFMA, bf16 out, stride 504)
//   out = relu(relu(agg(H2)+b2) @ W3 + b3)   (fused agg+layer3)

#define N_NODES 20000
#define N_EDGES 200000
#define D_IN    1433
#define D_H1    1000
#define D_H2    500
#define D_OUT   7

#define MPAD    20096        // 157 * 128
#define K1PAD   1472         // D_IN padded to mult of 64
#define N1PAD   1024
#define K2PAD   1024
#define N2PAD   512
#define H1STR   1008
#define H2STR   504
#define MBLK    157          // m-blocks of 128

typedef __attribute__((ext_vector_type(8))) short short8;
typedef __attribute__((ext_vector_type(8))) unsigned short ushort8_t;
typedef __attribute__((ext_vector_type(4))) float f32x4;

__device__ __forceinline__ unsigned short bf16_rne(float x) {
    unsigned int u = __float_as_uint(x);
    u = (u + 0x7FFFu + ((u >> 16) & 1u)) >> 16;
    return (unsigned short)u;
}
__device__ __forceinline__ float bf16_up(unsigned short h) {
    return __uint_as_float((unsigned int)h << 16);
}

__device__ __forceinline__ void gl_lds16(const unsigned short* g, unsigned short* lds) {
    __builtin_amdgcn_global_load_lds(
        (const __attribute__((address_space(1))) unsigned int*)g,
        (__attribute__((address_space(3))) unsigned int*)lds, 16, 0, 0);
}

// ---------------------------------------------------------------- CSR build
__global__ __launch_bounds__(256) void count_deg(const int* __restrict__ dst,
                                                 int* __restrict__ offs) {
    int e = blockIdx.x * 256 + threadIdx.x;
    if (e < N_EDGES) atomicAdd(&offs[dst[e] + 1], 1);
}

// single-block inclusive scan via wave shuffles; also fills cursor[i] = offs[i]
__global__ __launch_bounds__(1024) void scan_csr(int* __restrict__ offs,
                                                 int* __restrict__ cursor, int n) {
    __shared__ int wsum[16];
    __shared__ int s_carry;
    const int t = threadIdx.x, lane = t & 63, wv = t >> 6;
    if (t == 0) s_carry = 0;
    __syncthreads();
    for (int base = 0; base < n; base += 1024) {
        int i = base + t;
        int v = (i < n) ? offs[i] : 0;
        #pragma unroll
        for (int s = 1; s < 64; s <<= 1) {
            int u = __shfl_up(v, s, 64);
            if (lane >= s) v += u;
        }
        if (lane == 63) wsum[wv] = v;
        __syncthreads();
        int prefix = s_carry;
        for (int k = 0; k < wv; ++k) prefix += wsum[k];
        v += prefix;
        if (i < n) {
            offs[i] = v;
            if (i < N_NODES) cursor[i] = v;
        }
        __syncthreads();
        if (t == 1023) s_carry = v;
        // next-iteration barrier orders this write before the next reads
    }
}

__global__ __launch_bounds__(256) void fill_csr(const int* __restrict__ src,
                                                const int* __restrict__ dst,
                                                int* __restrict__ cursor,
                                                int* __restrict__ srcs) {
    int e = blockIdx.x * 256 + threadIdx.x;
    if (e < N_EDGES) {
        int pos = atomicAdd(&cursor[dst[e]], 1);
        srcs[pos] = src[e];
    }
}

// --------------------------------------------------------------- input casts
__global__ __launch_bounds__(256) void cast_features(const float* __restrict__ F,
                                                     unsigned int* __restrict__ out) {
    int row = blockIdx.x;
    int t = threadIdx.x;
    const float* fr = F + (size_t)row * D_IN;
    bool live = row < N_NODES;
    for (int kk = t; kk < K1PAD / 2; kk += 256) {
        int k0 = kk * 2;
        float a = (live && k0     < D_IN) ? fr[k0]     : 0.f;
        float b = (live && k0 + 1 < D_IN) ? fr[k0 + 1] : 0.f;
        out[(size_t)row * (K1PAD / 2) + kk] =
            (unsigned int)bf16_rne(a) | ((unsigned int)bf16_rne(b) << 16);
    }
}

template <int SR, int SC, int DR, int DC>
__global__ __launch_bounds__(256) void transpose_cast_pad(const float* __restrict__ src,
                                                          unsigned short* __restrict__ dst) {
    __shared__ float tile[32][33];
    int c0 = blockIdx.x * 32;
    int r0 = blockIdx.y * 32;
    int tx = threadIdx.x & 31, ty = threadIdx.x >> 5;
    #pragma unroll
    for (int p = 0; p < 4; ++p) {
        int r = r0 + ty + p * 8, c = c0 + tx;
        tile[ty + p * 8][tx] = (r < SR && c < SC) ? src[(size_t)r * SC + c] : 0.f;
    }
    __syncthreads();
    #pragma unroll
    for (int p = 0; p < 4; ++p) {
        int dr = c0 + ty + p * 8;
        int dc = r0 + tx;
        if (dr < DR && dc < DC) dst[(size_t)dr * DC + dc] = bf16_rne(tile[tx][ty + p * 8]);
    }
}

// -------------------------------------------------------------- bf16 MFMA GEMM
// C[M,N](bf16, stride OSTR) = A[MPAD,KPAD] @ B^T rows[NPAD,KPAD].
// XCD m-striping: xcd = bid&7 owns m-blocks {xcd, xcd+8, ...} -> A fetched once
// chip-wide (verified R4: FETCH 234->64 MB). Single LDS buffer, compiler waits.
// BK=64: 32 MFMAs per barrier-pair (vs 16 at BK=32) amortizes the vmcnt(0)
// barrier drain. LDS row = 64 shorts = 128 B == 32 banks, so rows alias banks:
// 8-slot XOR swizzle -- physical slot p of row r holds logical k-chunk p^(r&7).
// Staging lane l loads global chunk (l&7)^(l>>3) (rbase = 0 mod 8); fragment
// reads hit slot (s*4+quad)^(mrow&7): 16 lanes -> 8 slots x 2 = 2-way = free.
template <int KPAD, int NB>
__global__ __launch_bounds__(256) void gemm_mfma(const unsigned short* __restrict__ A,
                                                 const unsigned short* __restrict__ B,
                                                 unsigned short* __restrict__ C,
                                                 int M, int N, int OSTR) {
    __shared__ __align__(16) unsigned short sA[128 * 64];
    __shared__ __align__(16) unsigned short sB[128 * 64];
    const int bid = blockIdx.x;
    const int xcd = bid & 7;
    const int tt  = bid >> 3;
    const int nb  = tt % NB;
    const int mb  = (tt / NB) * 8 + xcd;
    if (mb >= MBLK) return;

    const int t = threadIdx.x;
    const int w = t >> 6, lane = t & 63;
    const int m0 = mb * 128, n0 = nb * 128;
    const int wm = (w >> 1) * 64, wn = (w & 1) * 64;

    const int srowo = lane >> 3;                       // row offset in 8-row group
    const int skc   = ((lane & 7) ^ srowo) * 8;        // XOR-swizzled global k-chunk
    const int mrow = lane & 15, quad = lane >> 4;

    const unsigned short* Aptr = A + (size_t)(m0 + srowo) * KPAD + skc;
    const unsigned short* Bptr = B + (size_t)(n0 + srowo) * KPAD + skc;

    f32x4 acc[4][4] = {};

    for (int k0 = 0; k0 < KPAD; k0 += 64) {
        #pragma unroll
        for (int c = 0; c < 4; ++c) {
            const int rbase = c * 32 + w * 8;          // 8-aligned
            gl_lds16(Aptr + (size_t)rbase * KPAD, &sA[rbase * 64]);
            gl_lds16(Bptr + (size_t)rbase * KPAD, &sB[rbase * 64]);
        }
        Aptr += 64; Bptr += 64;
        __syncthreads();

        #pragma unroll
        for (int s = 0; s < 2; ++s) {
            short8 af[4], bf[4];
            #pragma unroll
            for (int mt = 0; mt < 4; ++mt) {
                int r = wm + mt * 16 + mrow;
                af[mt] = *(const short8*)&sA[r * 64 + (((s * 4 + quad) ^ (mrow & 7)) * 8)];
            }
            #pragma unroll
            for (int nt = 0; nt < 4; ++nt) {
                int r = wn + nt * 16 + mrow;
                bf[nt] = *(const short8*)&sB[r * 64 + (((s * 4 + quad) ^ (mrow & 7)) * 8)];
            }
            #pragma unroll
            for (int mt = 0; mt < 4; ++mt)
                #pragma unroll
                for (int nt = 0; nt < 4; ++nt)
                    acc[mt][nt] = __builtin_amdgcn_mfma_f32_16x16x32_bf16(
                        af[mt], bf[nt], acc[mt][nt], 0, 0, 0);
        }
        __syncthreads();
    }

    // C/D layout: col = lane&15, row = quad*4 + reg
    #pragma unroll
    for (int mt = 0; mt < 4; ++mt) {
        int m = m0 + wm + mt * 16 + quad * 4;
        #pragma unroll
        for (int nt = 0; nt < 4; ++nt) {
            int n = n0 + wn + nt * 16 + mrow;
            if (n >= N) continue;
            #pragma unroll
            for (int r = 0; r < 4; ++r)
                if (m + r < M) C[(size_t)(m + r) * OSTR + n] = bf16_rne(acc[mt][nt][r]);
        }
    }
}

// -------------------------------- agg1: X1 = relu(agg(H1)+b1), bf16 -> bf16
// grid = MPAD: blocks >= N_NODES emit zero pad rows. 4-deep edge unroll keeps
// 4 independent 16B gathers in flight per lane (latency-bound L3 reads).
__global__ __launch_bounds__(128) void agg1_bf16(const unsigned short* __restrict__ H,
                                                 const int* __restrict__ offs,
                                                 const int* __restrict__ srcs,
                                                 const float* __restrict__ bias,
                                                 unsigned short* __restrict__ X) {
    const int i = blockIdx.x, t = threadIdx.x;
    const bool active = t < 125;
    const int tc = active ? t : 124;
    ushort8_t o = (ushort8_t)0;
    if (i < N_NODES) {
        const int beg = offs[i], end = offs[i + 1];
        const unsigned short* Hc = H + tc * 8;
        float s[8] = {};
        int e = beg;
        for (; e + 4 <= end; e += 4) {
            int j0 = srcs[e], j1 = srcs[e + 1], j2 = srcs[e + 2], j3 = srcs[e + 3];
            ushort8_t v0 = *(const ushort8_t*)(Hc + (size_t)j0 * H1STR);
            ushort8_t v1 = *(const ushort8_t*)(Hc + (size_t)j1 * H1STR);
            ushort8_t v2 = *(const ushort8_t*)(Hc + (size_t)j2 * H1STR);
            ushort8_t v3 = *(const ushort8_t*)(Hc + (size_t)j3 * H1STR);
            #pragma unroll
            for (int u = 0; u < 8; ++u)
                s[u] += (bf16_up(v0[u]) + bf16_up(v1[u])) +
                        (bf16_up(v2[u]) + bf16_up(v3[u]));
        }
        for (; e < end; ++e) {
            ushort8_t v = *(const ushort8_t*)(Hc + (size_t)srcs[e] * H1STR);
            #pragma unroll
            for (int u = 0; u < 8; ++u) s[u] += bf16_up(v[u]);
        }
        if (active) {
            #pragma unroll
            for (int u = 0; u < 8; ++u)
                o[u] = bf16_rne(fmaxf(s[u] + bias[t * 8 + u], 0.f));
        }
    }
    *(ushort8_t*)(X + (size_t)i * K2PAD + t * 8) = o;
}

// ---------------- agg2 + layer3: out = relu(relu(agg(H2)+b2) @ W3 + b3)
__global__ __launch_bounds__(128) void agg2_out(const unsigned short* __restrict__ H,
                                                const int* __restrict__ offs,
                                                const int* __restrict__ srcs,
                                                const float* __restrict__ b2,
                                                const float* __restrict__ W3,
                                                const float* __restrict__ b3,
                                                float* __restrict__ out) {
    __shared__ float red[2][8];
    const int i = blockIdx.x, t = threadIdx.x;
    const bool active = t < 125;
    const int tc = active ? t : 124;
    const int beg = offs[i], end = offs[i + 1];
    const unsigned short* Hc = H + tc * 4;
    float s[4] = {};
    int e = beg;
    for (; e + 4 <= end; e += 4) {
        int j0 = srcs[e], j1 = srcs[e + 1], j2 = srcs[e + 2], j3 = srcs[e + 3];
        ushort4 v0 = *(const ushort4*)(Hc + (size_t)j0 * H2STR);
        ushort4 v1 = *(const ushort4*)(Hc + (size_t)j1 * H2STR);
        ushort4 v2 = *(const ushort4*)(Hc + (size_t)j2 * H2STR);
        ushort4 v3 = *(const ushort4*)(Hc + (size_t)j3 * H2STR);
        s[0] += (bf16_up(v0.x) + bf16_up(v1.x)) + (bf16_up(v2.x) + bf16_up(v3.x));
        s[1] += (bf16_up(v0.y) + bf16_up(v1.y)) + (bf16_up(v2.y) + bf16_up(v3.y));
        s[2] += (bf16_up(v0.z) + bf16_up(v1.z)) + (bf16_up(v2.z) + bf16_up(v3.z));
        s[3] += (bf16_up(v0.w) + bf16_up(v1.w)) + (bf16_up(v2.w) + bf16_up(v3.w));
    }
    for (; e < end; ++e) {
        ushort4 v = *(const ushort4*)(Hc + (size_t)srcs[e] * H2STR);
        s[0] += bf16_up(v.x); s[1] += bf16_up(v.y);
        s[2] += bf16_up(v.z); s[3] += bf16_up(v.w);
    }
    float acc[D_OUT] = {};
    if (active) {
        #pragma unroll
        for (int u = 0; u < 4; ++u) {
            float x = fmaxf(s[u] + b2[t * 4 + u], 0.f);
            const float* wr = W3 + (size_t)(t * 4 + u) * D_OUT;
            #pragma unroll
            for (int j = 0; j < D_OUT; ++j) acc[j] += x * wr[j];
        }
    }
    #pragma unroll
    for (int j = 0; j < D_OUT; ++j)
        #pragma unroll
        for (int off = 32; off; off >>= 1) acc[j] += __shfl_down(acc[j], off);
    const int lane = t & 63, wave = t >> 6;
    if (lane == 0) {
        #pragma unroll
        for (int j = 0; j < D_OUT; ++j) red[wave][j] = acc[j];
    }
    __syncthreads();
    if (t == 0) {
        #pragma unroll
        for (int j = 0; j < D_OUT; ++j)
            out[(size_t)i * D_OUT + j] = fmaxf(red[0][j] + red[1][j] + b3[j], 0.f);
    }
}

// ---------------------------------------------------------------------- launch
extern "C" void kernel_launch(void* const* d_in, const int* in_sizes, int n_in,
                              void* d_out, int out_size, void* d_ws, size_t ws_size,
                              hipStream_t stream) {
    const float* features = (const float*)d_in[0];
    const int*   src      = (const int*)d_in[1];
    const int*   dst      = (const int*)d_in[2];
    const float* W1       = (const float*)d_in[3];
    const float* b1       = (const float*)d_in[4];
    const float* W2       = (const float*)d_in[5];
    const float* b2       = (const float*)d_in[6];
    const float* W3       = (const float*)d_in[7];
    const float* b3       = (const float*)d_in[8];
    float* out = (float*)d_out;

    char* ws = (char*)d_ws;
    unsigned short* Fbf  = (unsigned short*)(ws + 0);          // [MPAD][K1PAD]  59,162,624 B
    unsigned short* X1bf = (unsigned short*)(ws + 0);          // [MPAD][K2PAD]  41,156,608 B (overlay)
    unsigned short* H1   = (unsigned short*)(ws + 59162624);   // [20000][H1STR] 40,320,000 B
    unsigned short* H2   = (unsigned short*)(ws + 59162624);   // [20000][H2STR] 20,160,000 B (overlay)
    unsigned short* W1T  = (unsigned short*)(ws + 99482624);   // [N1PAD][K1PAD]  3,014,656 B
    unsigned short* W2T  = (unsigned short*)(ws + 102497280);  // [N2PAD][K2PAD]  1,048,576 B
    int* offs   = (int*)(ws + 103545856);
    int* cursor = (int*)(ws + 103625984);
    int* srcs   = (int*)(ws + 103706112);

    // ---- CSR build
    hipMemsetAsync(offs, 0, (N_NODES + 1) * sizeof(int), stream);
    count_deg<<<(N_EDGES + 255) / 256, 256, 0, stream>>>(dst, offs);
    scan_csr<<<1, 1024, 0, stream>>>(offs, cursor, N_NODES + 1);
    fill_csr<<<(N_EDGES + 255) / 256, 256, 0, stream>>>(src, dst, cursor, srcs);

    // ---- casts
    cast_features<<<MPAD, 256, 0, stream>>>(features, (unsigned int*)Fbf);
    transpose_cast_pad<D_IN, D_H1, N1PAD, K1PAD>
        <<<dim3(N1PAD / 32, K1PAD / 32), 256, 0, stream>>>(W1, W1T);
    transpose_cast_pad<D_H1, D_H2, N2PAD, K2PAD>
        <<<dim3(N2PAD / 32, K2PAD / 32), 256, 0, stream>>>(W2, W2T);

    // ---- layer 1: H1 = F @ W1; X1 = relu(agg(H1)+b1) (pad rows zeroed in-kernel)
    gemm_mfma<K1PAD, N1PAD / 128><<<8 * (N1PAD / 128) * 20, 256, 0, stream>>>(
        Fbf, W1T, H1, N_NODES, D_H1, H1STR);
    agg1_bf16<<<MPAD, 128, 0, stream>>>(H1, offs, srcs, b1, X1bf);

    // ---- layer 2: H2 = X1 @ W2; out = fused agg2 + layer3
    gemm_mfma<K2PAD, N2PAD / 128><<<8 * (N2PAD / 128) * 20, 256, 0, stream>>>(
        X1bf, W2T, H2, N_NODES, D_H2, H2STR);
    agg2_out<<<N_NODES, 128, 0, stream>>>(H2, offs, srcs, b2, W3, b3, out);
}